// Round 7
// baseline (312.891 us; speedup 1.0000x reference)
//
#include <hip/hip_runtime.h>
#include <hip/hip_bf16.h>

// Problem constants (fixed by the reference)
#define LATENT 32
#define HID 64
#define NB 256          // batch (graphs)
#define NN 200000       // nodes
#define NE 1500000      // edges
#define TWOH 128        // 2*HID

// Output layout (flat floats in d_out)
#define OUT_NODE_OFF   0
#define OUT_EDGE_OFF   (NN * 4)                   // 800000
#define OUT_ENERGY_OFF (OUT_EDGE_OFF + NE * 3)    // 5300000
#define OUT_STRESS_OFF (OUT_ENERGY_OFF + NB * 2)  // 5300512

// Workspace layout (flat floats in d_ws)
#define WS_ZPROJ 0
#define WS_ZC    (WS_ZPROJ + NB*TWOH)
#define WS_P1    (WS_ZC + NB*HID)
#define WS_P2    (WS_P1 + NB*HID)
#define WS_T4    (WS_P2 + NB*HID)
#define WS_W1H   (WS_T4 + NB*NB*4)      // fp16 [128ch1][128k]  (plain transpose)
#define WS_W2P   (WS_W1H + 8192)        // fp16 [64ch2][128k']  (K-permuted, see below)

typedef _Float16 half8 __attribute__((ext_vector_type(8)));
typedef _Float16 half4 __attribute__((ext_vector_type(4)));
typedef float f32x4 __attribute__((ext_vector_type(4)));
typedef int i32x2 __attribute__((ext_vector_type(2)));
typedef int i32x4 __attribute__((ext_vector_type(4)));

#define NODE_B 3125             // node blocks: 4 waves x 1 tile = 64 nodes/block
#define EDGE_B 1465             // edge blocks: 256 thr x 4 edges = 1024 edges
// ---------------------------------------------------------------------------
// K-permutation for stage 2 (kills the cross-lane exchange):
// Stage-1 D layout gives lane (node=lrow, kg) the values nep[lrow][16*cht+4*kg+r]
// in acc regs (cht=0..7, r=0..3). Declaring stage-2's K index as
//   ch(kperm) = 32*kb' + 16*(j>>2) + 4*kg + (j&3),  kperm = kb'*32 + kg*8 + j
// makes the B-fragment for MFMA kb' exactly (vv[2kb'], vv[2kb'+1]) — a bitcast.
// w2p must hold W2 with its K dim stored in kperm order (done in prep).
// ---------------------------------------------------------------------------

// ---------------------------------------------------------------------------
// Kernel 1: per-graph precompute (blocks 0..255) + weight prep (256..319).
// ---------------------------------------------------------------------------
__global__ void precompute_kernel(
    const float* __restrict__ z,
    const float* __restrict__ lp_w, const float* __restrict__ lp_b,
    const float* __restrict__ nd1_w,
    const float* __restrict__ ed1_w,
    const float* __restrict__ en1_w, const float* __restrict__ en1_b,
    const float* __restrict__ en2_w, const float* __restrict__ en2_b,
    const float* __restrict__ st1_w, const float* __restrict__ st1_b,
    const float* __restrict__ st2_w, const float* __restrict__ st2_b,
    const float* __restrict__ nep_w,
    float* __restrict__ z_proj, float* __restrict__ zc,
    float* __restrict__ P1, float* __restrict__ P2,
    _Float16* __restrict__ w1h, _Float16* __restrict__ w2p,
    float* __restrict__ out_energy, float* __restrict__ out_stress)
{
    const int t = threadIdx.x;

    if (blockIdx.x >= NB) {
        const int i = (blockIdx.x - NB) * 256 + t;
        if (i < TWOH * TWOH) {
            const int ch1 = i >> 7, k = i & 127;
            w1h[i] = (_Float16)nep_w[k * TWOH + ch1];   // [ch1][k]
        }
        if (i < HID * TWOH) {
            const int ch2 = i >> 7, tp = i & 127;
            const int kbp = tp >> 5, kg = (tp >> 3) & 3, j = tp & 7;
            const int ch = kbp * 32 + ((j >> 2) << 4) + kg * 4 + (j & 3);
            w2p[i] = (_Float16)nd1_w[ch * HID + ch2];   // [ch2][kperm]
        }
        return;
    }

    const int b = blockIdx.x;
    __shared__ float zrow[LATENT];
    __shared__ float zp[TWOH];
    __shared__ float h_en[HID];
    __shared__ float h_st[HID];

    if (t < LATENT) zrow[t] = z[b * LATENT + t];
    __syncthreads();

    if (t < TWOH) {
        float a = lp_b[t];
        #pragma unroll
        for (int k = 0; k < LATENT; ++k)
            a = fmaf(zrow[k], lp_w[k * TWOH + t], a);
        a = fmaxf(a, 0.f);
        zp[t] = a;
        z_proj[b * TWOH + t] = a;
    }
    if (t < HID) {
        float ae = en1_b[t];
        float as = st1_b[t];
        #pragma unroll
        for (int k = 0; k < LATENT; ++k) {
            ae = fmaf(zrow[k], en1_w[k * HID + t], ae);
            as = fmaf(zrow[k], st1_w[k * HID + t], as);
        }
        h_en[t] = fmaxf(ae, 0.f);
        h_st[t] = fmaxf(as, 0.f);
    }
    __syncthreads();

    if (t < HID) {
        float a = 0.f, p1 = 0.f, p2 = 0.f;
        #pragma unroll 8
        for (int k = 0; k < TWOH; ++k) {
            const float zk = zp[k];
            a  = fmaf(zk, nd1_w[k * HID + t], a);
            p1 = fmaf(zk, ed1_w[k * HID + t], p1);
            p2 = fmaf(zk, ed1_w[(TWOH + k) * HID + t], p2);
        }
        zc[b * HID + t] = a;
        P1[b * HID + t] = p1;
        P2[b * HID + t] = p2;
    }
    if (t < 2) {
        float a = en2_b[t];
        #pragma unroll 8
        for (int k = 0; k < HID; ++k) a = fmaf(h_en[k], en2_w[k * 2 + t], a);
        out_energy[b * 2 + t] = a;
    }
    if (t >= 16 && t < 25) {
        const int j = t - 16;
        float a = st2_b[j];
        #pragma unroll 8
        for (int k = 0; k < HID; ++k) a = fmaf(h_st[k], st2_w[k * 9 + j], a);
        out_stress[b * 9 + j] = a;
    }
}

// ---------------------------------------------------------------------------
// Kernel 2: edge pair table. grid=256 (gs), block=256 (gd).
// ---------------------------------------------------------------------------
__global__ void edge_table_kernel(
    const float* __restrict__ P1, const float* __restrict__ P2,
    const float* __restrict__ ed1_b,
    const float* __restrict__ ed2_w, const float* __restrict__ ed2_b,
    float4* __restrict__ T4)
{
    const int gs = blockIdx.x;
    const int t  = threadIdx.x;

    __shared__ float p1s[HID];
    __shared__ float w2s_[HID * 3];
    __shared__ float b2s[3];

    if (t < HID) p1s[t] = P1[gs * HID + t] + ed1_b[t];
    if (t >= 64 && t < 64 + HID * 3) w2s_[t - 64] = ed2_w[t - 64];
    if (t < 3) b2s[t] = ed2_b[t];
    __syncthreads();

    float o0 = b2s[0], o1 = b2s[1], o2 = b2s[2];
    const f32x4* __restrict__ p2 = reinterpret_cast<const f32x4*>(&P2[t * HID]);
    #pragma unroll 4
    for (int k4 = 0; k4 < 16; ++k4) {
        const f32x4 pv = p2[k4];
        #pragma unroll
        for (int j = 0; j < 4; ++j) {
            const int k = k4 * 4 + j;
            const float h = fmaxf(p1s[k] + pv[j], 0.f);
            o0 = fmaf(h, w2s_[k * 3 + 0], o0);
            o1 = fmaf(h, w2s_[k * 3 + 1], o1);
            o2 = fmaf(h, w2s_[k * 3 + 2], o2);
        }
    }
    T4[gs * NB + t] = make_float4(o0, o1, o2, 0.f);
}

// ---------------------------------------------------------------------------
// Kernel 3: node + edge. ZERO LDS, ZERO barriers, max occupancy.
//  Node blocks [0, NODE_B): 4 independent waves, 1 16-node tile each.
//   - emb B-frags direct from global (each byte read once per wave)
//   - W1/W2 fragments direct from global -> L1-resident (48 KB/CU)
//   - stage1->stage2 handoff IN REGISTERS via the w2p K-permutation (no shfl)
//   - stage3 in-register, 8 shfl_xor, coalesced f32x4 store
//  Edge blocks [NODE_B, +EDGE_B): 1024-edge gathers from the pair table.
// ---------------------------------------------------------------------------
__global__ __launch_bounds__(256, 6)
void node_edge_kernel(
    const float* __restrict__ node_emb,
    const int*   __restrict__ graph_id,
    const _Float16* __restrict__ w1h,
    const float* __restrict__ nep_b,
    const _Float16* __restrict__ w2p,
    const float* __restrict__ nd1_b,
    const float* __restrict__ nd2_w, const float* __restrict__ nd2_b,
    const float* __restrict__ zc,
    const int* __restrict__ src, const int* __restrict__ dst,
    const float4* __restrict__ T4,
    float* __restrict__ out_node, float* __restrict__ out_edge)
{
    const int tid = threadIdx.x;
    const int bid = blockIdx.x;

    if (bid >= NODE_B) {
        // ---------------- edge path ----------------
        const int e0 = ((bid - NODE_B) * 256 + tid) * 4;
        if (e0 >= NE) return;
        const int4 s4 = *reinterpret_cast<const int4*>(&src[e0]);
        const int4 d4 = *reinterpret_cast<const int4*>(&dst[e0]);
        const int ss[4] = {s4.x, s4.y, s4.z, s4.w};
        const int dd[4] = {d4.x, d4.y, d4.z, d4.w};
        float o[12];
        #pragma unroll
        for (int j = 0; j < 4; ++j) {
            const int gs = graph_id[ss[j]];
            const int gd = graph_id[dd[j]];
            const float4 tv = T4[gs * NB + gd];
            o[j * 3 + 0] = tv.x; o[j * 3 + 1] = tv.y; o[j * 3 + 2] = tv.z;
        }
        float4* outp = reinterpret_cast<float4*>(&out_edge[(size_t)e0 * 3]);
        outp[0] = make_float4(o[0], o[1], o[2],  o[3]);
        outp[1] = make_float4(o[4], o[5], o[6],  o[7]);
        outp[2] = make_float4(o[8], o[9], o[10], o[11]);
        return;
    }

    // ---------------- node path: one 16-node tile per wave ----------------
    const int wv   = tid >> 6;
    const int lane = tid & 63;
    const int lrow = lane & 15;     // node within tile / M-row within frag
    const int kg   = lane >> 4;     // k-group
    const int tile = bid * 4 + wv;  // 0..12499 exactly
    const int node = tile * 16 + lrow;

    const int g = graph_id[node];

    // ---- stage 1: nep^T = relu(W1^T @ emb^T + b1) ----
    f32x4 acc1[8];
    #pragma unroll
    for (int cht = 0; cht < 8; ++cht)
        acc1[cht] = *reinterpret_cast<const f32x4*>(&nep_b[cht * 16 + kg * 4]);

    const float* ep = node_emb + (size_t)node * TWOH + kg * 8;
    __builtin_amdgcn_s_setprio(1);
    #pragma unroll
    for (int kb = 0; kb < 4; ++kb) {
        const f32x4 u = *reinterpret_cast<const f32x4*>(ep + kb * 32);
        const f32x4 v = *reinterpret_cast<const f32x4*>(ep + kb * 32 + 4);
        half8 h;
        h[0] = (_Float16)u[0]; h[1] = (_Float16)u[1];
        h[2] = (_Float16)u[2]; h[3] = (_Float16)u[3];
        h[4] = (_Float16)v[0]; h[5] = (_Float16)v[1];
        h[6] = (_Float16)v[2]; h[7] = (_Float16)v[3];
        #pragma unroll
        for (int cht = 0; cht < 8; ++cht) {
            const half8 w = *reinterpret_cast<const half8*>(
                &w1h[(cht * 16 + lrow) * TWOH + kb * 32 + kg * 8]);
            acc1[cht] = __builtin_amdgcn_mfma_f32_16x16x32_f16(
                w, h, acc1[cht], 0, 0, 0);
        }
    }
    __builtin_amdgcn_s_setprio(0);

    // relu -> fp16; these ARE the stage-2 B-fragments (w2p K-permutation)
    half4 vv[8];
    #pragma unroll
    for (int cht = 0; cht < 8; ++cht) {
        #pragma unroll
        for (int j = 0; j < 4; ++j)
            vv[cht][j] = (_Float16)fmaxf(acc1[cht][j], 0.f);
    }

    // ---- stage 2: tt^T = relu(W2p @ nep^T + b2 + zc[g]) ----
    f32x4 acc2[4];
    #pragma unroll
    for (int c2 = 0; c2 < 4; ++c2)
        acc2[c2] = *reinterpret_cast<const f32x4*>(&nd1_b[c2 * 16 + kg * 4])
                 + *reinterpret_cast<const f32x4*>(&zc[(size_t)g * HID + c2 * 16 + kg * 4]);

    __builtin_amdgcn_s_setprio(1);
    #pragma unroll
    for (int kbp = 0; kbp < 4; ++kbp) {
        const i32x2 lo = __builtin_bit_cast(i32x2, vv[2 * kbp]);
        const i32x2 hi = __builtin_bit_cast(i32x2, vv[2 * kbp + 1]);
        i32x4 c; c.x = lo.x; c.y = lo.y; c.z = hi.x; c.w = hi.y;
        const half8 nB = __builtin_bit_cast(half8, c);
        #pragma unroll
        for (int c2 = 0; c2 < 4; ++c2) {
            const half8 w = *reinterpret_cast<const half8*>(
                &w2p[(c2 * 16 + lrow) * TWOH + kbp * 32 + kg * 8]);
            acc2[c2] = __builtin_amdgcn_mfma_f32_16x16x32_f16(
                w, nB, acc2[c2], 0, 0, 0);
        }
    }
    __builtin_amdgcn_s_setprio(0);

    // ---- stage 3: out = tt @ W3 + b3; reduce over kg via shfl_xor ----
    f32x4 p = {0.f, 0.f, 0.f, 0.f};
    #pragma unroll
    for (int c2 = 0; c2 < 4; ++c2) {
        #pragma unroll
        for (int r = 0; r < 4; ++r) {
            const float tval = fmaxf(acc2[c2][r], 0.f);
            const f32x4 w3v = *reinterpret_cast<const f32x4*>(
                &nd2_w[(c2 * 16 + kg * 4 + r) * 4]);
            p += tval * w3v;
        }
    }
    #pragma unroll
    for (int j = 0; j < 4; ++j) {
        p[j] += __shfl_xor(p[j], 16, 64);
        p[j] += __shfl_xor(p[j], 32, 64);
    }
    if (kg == 0) {
        const f32x4 b3 = *reinterpret_cast<const f32x4*>(&nd2_b[0]);
        *reinterpret_cast<f32x4*>(&out_node[(size_t)node * 4]) = p + b3;
    }
}

// ---------------------------------------------------------------------------
extern "C" void kernel_launch(void* const* d_in, const int* in_sizes, int n_in,
                              void* d_out, int out_size, void* d_ws, size_t ws_size,
                              hipStream_t stream)
{
    const float* z        = (const float*)d_in[0];
    const float* node_emb = (const float*)d_in[1];
    const int*   graph_id = (const int*)  d_in[2];
    const int*   src      = (const int*)  d_in[3];
    const int*   dst      = (const int*)  d_in[4];
    const float* lp_w  = (const float*)d_in[5];
    const float* lp_b  = (const float*)d_in[6];
    const float* nep_w = (const float*)d_in[7];
    const float* nep_b = (const float*)d_in[8];
    const float* nd1_w = (const float*)d_in[9];
    const float* nd1_b = (const float*)d_in[10];
    const float* nd2_w = (const float*)d_in[11];
    const float* nd2_b = (const float*)d_in[12];
    const float* ed1_w = (const float*)d_in[13];
    const float* ed1_b = (const float*)d_in[14];
    const float* ed2_w = (const float*)d_in[15];
    const float* ed2_b = (const float*)d_in[16];
    const float* en1_w = (const float*)d_in[17];
    const float* en1_b = (const float*)d_in[18];
    const float* en2_w = (const float*)d_in[19];
    const float* en2_b = (const float*)d_in[20];
    const float* st1_w = (const float*)d_in[21];
    const float* st1_b = (const float*)d_in[22];
    const float* st2_w = (const float*)d_in[23];
    const float* st2_b = (const float*)d_in[24];

    float* out = (float*)d_out;
    float* out_node   = out + OUT_NODE_OFF;
    float* out_edge   = out + OUT_EDGE_OFF;
    float* out_energy = out + OUT_ENERGY_OFF;
    float* out_stress = out + OUT_STRESS_OFF;

    float* ws     = (float*)d_ws;
    float* z_proj = ws + WS_ZPROJ;
    float* zc     = ws + WS_ZC;
    float* P1     = ws + WS_P1;
    float* P2     = ws + WS_P2;
    float4* T4    = (float4*)(ws + WS_T4);
    _Float16* w1h = (_Float16*)(ws + WS_W1H);
    _Float16* w2p = (_Float16*)(ws + WS_W2P);

    precompute_kernel<<<NB + 64, 256, 0, stream>>>(
        z, lp_w, lp_b, nd1_w, ed1_w,
        en1_w, en1_b, en2_w, en2_b, st1_w, st1_b, st2_w, st2_b, nep_w,
        z_proj, zc, P1, P2, w1h, w2p, out_energy, out_stress);

    edge_table_kernel<<<NB, NB, 0, stream>>>(P1, P2, ed1_b, ed2_w, ed2_b, T4);

    node_edge_kernel<<<NODE_B + EDGE_B, 256, 0, stream>>>(
        node_emb, graph_id, w1h, nep_b, w2p, nd1_b, nd2_w, nd2_b, zc,
        src, dst, T4, out_node, out_edge);
}